// Round 11
// baseline (498.943 us; speedup 1.0000x reference)
//
#include <hip/hip_runtime.h>
#include <hip/hip_bf16.h>
#include <math.h>

typedef __hip_bfloat16 bf16;
typedef __attribute__((ext_vector_type(8))) short short8;   // 8 bf16 (4 VGPRs)
typedef __attribute__((ext_vector_type(4))) float f32x4;
#define DEVINL __device__ __forceinline__

constexpr int Bc  = 2;
constexpr int Nc  = 768;
constexpr int Dc  = 512;
constexpr int Hc  = 8;
constexpr int DKc = 64;
constexpr int BHc = Bc * Hc;
constexpr float SCALE    = 0.125f;   // 1/sqrt(64)
constexpr float EPSF     = 1e-6f;
constexpr float BETA_NOT = 0.5f;

DEVINL float ldf(const float* p, long i) { return p[i]; }
DEVINL float ldf(const bf16* p, long i) { return __bfloat162float(p[i]); }
DEVINL void stf(float* p, long i, float v) { p[i] = v; }
DEVINL void stf(bf16* p, long i, float v) { p[i] = __float2bfloat16(v); }

DEVINL float sigf(float x) { return __fdividef(1.f, 1.f + __expf(-x)); }

// async global->LDS, 16B per lane; LDS dest = wave-uniform base + lane*16.
DEVINL void gl_lds16(const void* g, void* l) {
    __builtin_amdgcn_global_load_lds(
        (const __attribute__((address_space(1))) void*)g,
        (__attribute__((address_space(3))) void*)l, 16, 0, 0);
}

// ---------------------------------------------------------------------------
// Dtype sniffer — vectorized (validated round 9).
// ---------------------------------------------------------------------------
DEVINL int sniff_is_fp32(const void* xraw) {
    const uint4* p4 = (const uint4*)xraw;
    float mx = 0.f;
#pragma unroll
    for (int j = 0; j < 16; ++j) {
        const uint4 u = p4[j];
        const unsigned w[4] = {u.x, u.y, u.z, u.w};
#pragma unroll
        for (int t = 0; t < 4; ++t) {
            mx = fmaxf(mx, fabsf(__uint_as_float((w[t] & 0xffffu) << 16)));
            mx = fmaxf(mx, fabsf(__uint_as_float(w[t] & 0xffff0000u)));
        }
    }
    return mx > 1000.f ? 1 : 0;
}

DEVINL float cvt_elem(const void* s, long j, int is32) {
    return is32 ? ((const float*)s)[j]
                : __bfloat162float(((const bf16*)s)[j]);
}

__global__ __launch_bounds__(256) void convert_all(
    const void* x, const void* w1, const void* w2, const void* pw,
    const void* c1w, const void* c1b, const void* c2w, const void* c2b,
    const void* ch,
    bf16* xb, bf16* w1b, bf16* w2b, bf16* pwb, float* smallf)
{
    __shared__ int is32s;
    if (threadIdx.x == 0) is32s = sniff_is_fp32(x);
    __syncthreads();
    const int is32 = is32s;
    const long i = (long)blockIdx.x * 256 + threadIdx.x;
    if (i < (long)Bc * Nc * Dc) {
        xb[i]  = __float2bfloat16(cvt_elem(x,  i, is32));
        w1b[i] = __float2bfloat16(cvt_elem(w1, i, is32));
        w2b[i] = __float2bfloat16(cvt_elem(w2, i, is32));
    }
    if (i < (long)Dc * Dc) pwb[i] = __float2bfloat16(cvt_elem(pw, i, is32));
    if (i < 96)       smallf[i] = cvt_elem(c1w, i,        is32);
    else if (i < 112) smallf[i] = cvt_elem(c1b, i - 96,   is32);
    else if (i < 176) smallf[i] = cvt_elem(c2w, i - 112,  is32);
    else if (i < 180) smallf[i] = cvt_elem(c2b, i - 176,  is32);
    else if (i == 180) smallf[180] = cvt_elem(ch, 0, is32);
}

__global__ __launch_bounds__(256) void fill_sentinel(unsigned short* o) {
    const long i = (long)blockIdx.x * 256 + threadIdx.x;
    if (i < (long)Bc * Nc * Dc) o[i] = 0x40E0;  // bf16 7.0
}

// ---------------------------------------------------------------------------
// Generic bf16 transpose, 64x64 tiles: dst[c][r] = src[r][c]; src is (R,C).
// ---------------------------------------------------------------------------
__global__ __launch_bounds__(256) void transpose_bf16(
    const unsigned short* __restrict__ src, unsigned short* __restrict__ dst,
    int R, int C, long sS, long sD)
{
    __shared__ unsigned short tile[64][68];
    const unsigned short* s = src + (long)blockIdx.z * sS;
    unsigned short* d = dst + (long)blockIdx.z * sD;
    const int r0 = blockIdx.y * 64, c0 = blockIdx.x * 64;
    const int t = threadIdx.x;
    const int lr = t >> 4, lc4 = (t & 15) * 4;
#pragma unroll
    for (int i = 0; i < 4; ++i) {
        int r = lr + i * 16;
        *(uint2*)&tile[r][lc4] = *(const uint2*)&s[(long)(r0 + r) * C + c0 + lc4];
    }
    __syncthreads();
#pragma unroll
    for (int i = 0; i < 4; ++i) {
        int r = lr + i * 16;
        unsigned short v[4];
#pragma unroll
        for (int j = 0; j < 4; ++j) v[j] = tile[lc4 + j][r];
        *(uint2*)&d[(long)(c0 + r) * R + r0 + lc4] = *(uint2*)v;
    }
}

// ---------------------------------------------------------------------------
// MFMA bf16 NT GEMM with global_load_lds staging (validated rounds 6-10):
// C = A(M,K) @ Bt(N,K)^T. 128x128 tile, BK=32.
// XORB: B batch index = z^16 (merged Cr/Cl trick; adjacency-dependent).
// ---------------------------------------------------------------------------
template <int EPI, typename TC, int XORB = 0>
__global__ __launch_bounds__(256) void gemm_nt_mfma(
    const bf16* __restrict__ Ag, const bf16* __restrict__ Btg,
    TC* __restrict__ Cg, int M, int N, int K,
    long sA, long sB, long sC, float alpha)
{
    __shared__ unsigned short Asm[128 * 32];
    __shared__ unsigned short Bsm[128 * 32];

    const int tid  = threadIdx.x;
    const int wv   = tid >> 6;
    const int lane = tid & 63;
    const int q    = lane >> 4;
    const int ln   = lane & 15;
    const int wm   = wv & 1;
    const int wn   = wv >> 1;

    const int zb = XORB ? ((int)blockIdx.z ^ 16) : (int)blockIdx.z;
    const bf16* A  = Ag  + (long)blockIdx.z * sA + (long)(blockIdx.y * 128) * K;
    const bf16* Bt = Btg + (long)zb * sB + (long)(blockIdx.x * 128) * K;
    TC*         C  = Cg  + (long)blockIdx.z * sC;

    const int sr = lane >> 2, sc = lane & 3;
    const bf16* gA0 = A  + (long)(wv * 32 + sr)      * K + sc * 8;
    const bf16* gA1 = A  + (long)(wv * 32 + 16 + sr) * K + sc * 8;
    const bf16* gB0 = Bt + (long)(wv * 32 + sr)      * K + sc * 8;
    const bf16* gB1 = Bt + (long)(wv * 32 + 16 + sr) * K + sc * 8;
    unsigned short* lA0 = &Asm[(wv * 32)      * 32];
    unsigned short* lA1 = &Asm[(wv * 32 + 16) * 32];
    unsigned short* lB0 = &Bsm[(wv * 32)      * 32];
    unsigned short* lB1 = &Bsm[(wv * 32 + 16) * 32];

    f32x4 acc[4][4];
#pragma unroll
    for (int i = 0; i < 4; ++i)
#pragma unroll
        for (int j = 0; j < 4; ++j)
            acc[i][j] = (f32x4){0.f, 0.f, 0.f, 0.f};

    for (int k0 = 0; k0 < K; k0 += 32) {
        __syncthreads();
        gl_lds16(gA0 + k0, lA0);
        gl_lds16(gA1 + k0, lA1);
        gl_lds16(gB0 + k0, lB0);
        gl_lds16(gB1 + k0, lB1);
        __syncthreads();

        short8 af[4], bfr[4];
#pragma unroll
        for (int mt = 0; mt < 4; ++mt) {
            int m = wm * 64 + mt * 16 + ln;
            af[mt] = *(const short8*)&Asm[m * 32 + q * 8];
        }
#pragma unroll
        for (int nt = 0; nt < 4; ++nt) {
            int n = wn * 64 + nt * 16 + ln;
            bfr[nt] = *(const short8*)&Bsm[n * 32 + q * 8];
        }
#pragma unroll
        for (int mt = 0; mt < 4; ++mt)
#pragma unroll
            for (int nt = 0; nt < 4; ++nt)
                acc[mt][nt] = __builtin_amdgcn_mfma_f32_16x16x32_bf16(
                    af[mt], bfr[nt], acc[mt][nt], 0, 0, 0);
    }

#pragma unroll
    for (int mt = 0; mt < 4; ++mt) {
#pragma unroll
        for (int nt = 0; nt < 4; ++nt) {
            const int col = blockIdx.x * 128 + wn * 64 + nt * 16 + ln;
            const int rowb = blockIdx.y * 128 + wm * 64 + mt * 16 + q * 4;
#pragma unroll
            for (int r = 0; r < 4; ++r) {
                float v = acc[mt][nt][r] * alpha;
                if (EPI == 1) v = __logf(fmaxf(v, 0.f) + EPSF);
                stf(C, (long)(rowb + r) * N + col, v);
            }
        }
    }
}

// ---------------------------------------------------------------------------
// QKV via MFMA, merged sets (validated rounds 6-10).
// ---------------------------------------------------------------------------
__global__ __launch_bounds__(256) void qkv_mfma(
    const bf16* __restrict__ X,
    const bf16* __restrict__ w1t, const bf16* __restrict__ w2t,
    bf16* __restrict__ q1, bf16* __restrict__ k1, bf16* __restrict__ v1,
    bf16* __restrict__ q2, bf16* __restrict__ k2, bf16* __restrict__ v2)
{
    constexpr int K = Dc;  // 512
    __shared__ unsigned short Asm[128 * 32];
    __shared__ unsigned short Bsm[128 * 32];

    const int tid  = threadIdx.x;
    const int wv   = tid >> 6;
    const int lane = tid & 63;
    const int q    = lane >> 4;
    const int ln   = lane & 15;
    const int wm   = wv & 1;
    const int wn   = wv >> 1;
    const int set  = blockIdx.z;

    const bf16* Wt = set ? w2t : w1t;
    bf16* Q  = set ? q2 : q1;
    bf16* Ko = set ? k2 : k1;
    bf16* V  = set ? v2 : v1;

    const bf16* A  = X  + (long)(blockIdx.y * 128) * K;
    const bf16* Bt = Wt + (long)(blockIdx.x * 128) * K;

    const int sr = lane >> 2, sc = lane & 3;
    const bf16* gA0 = A  + (long)(wv * 32 + sr)      * K + sc * 8;
    const bf16* gA1 = A  + (long)(wv * 32 + 16 + sr) * K + sc * 8;
    const bf16* gB0 = Bt + (long)(wv * 32 + sr)      * K + sc * 8;
    const bf16* gB1 = Bt + (long)(wv * 32 + 16 + sr) * K + sc * 8;
    unsigned short* lA0 = &Asm[(wv * 32)      * 32];
    unsigned short* lA1 = &Asm[(wv * 32 + 16) * 32];
    unsigned short* lB0 = &Bsm[(wv * 32)      * 32];
    unsigned short* lB1 = &Bsm[(wv * 32 + 16) * 32];

    f32x4 acc[4][4];
#pragma unroll
    for (int i = 0; i < 4; ++i)
#pragma unroll
        for (int j = 0; j < 4; ++j)
            acc[i][j] = (f32x4){0.f, 0.f, 0.f, 0.f};

    for (int k0 = 0; k0 < K; k0 += 32) {
        __syncthreads();
        gl_lds16(gA0 + k0, lA0);
        gl_lds16(gA1 + k0, lA1);
        gl_lds16(gB0 + k0, lB0);
        gl_lds16(gB1 + k0, lB1);
        __syncthreads();

        short8 af[4], bfr[4];
#pragma unroll
        for (int mt = 0; mt < 4; ++mt) {
            int m = wm * 64 + mt * 16 + ln;
            af[mt] = *(const short8*)&Asm[m * 32 + q * 8];
        }
#pragma unroll
        for (int nt = 0; nt < 4; ++nt) {
            int n = wn * 64 + nt * 16 + ln;
            bfr[nt] = *(const short8*)&Bsm[n * 32 + q * 8];
        }
#pragma unroll
        for (int mt = 0; mt < 4; ++mt)
#pragma unroll
            for (int nt = 0; nt < 4; ++nt)
                acc[mt][nt] = __builtin_amdgcn_mfma_f32_16x16x32_bf16(
                    af[mt], bfr[nt], acc[mt][nt], 0, 0, 0);
    }

#pragma unroll
    for (int mt = 0; mt < 4; ++mt) {
#pragma unroll
        for (int nt = 0; nt < 4; ++nt) {
            const int col  = blockIdx.x * 128 + wn * 64 + nt * 16 + ln;
            const int rowb = blockIdx.y * 128 + wm * 64 + mt * 16 + q * 4;
            const int t = col >> 9;
            const int h = (col >> 6) & 7;
            const int dk = col & 63;
            bf16* dst = (t == 0) ? Q : (t == 1) ? Ko : V;
#pragma unroll
            for (int r = 0; r < 4; ++r) {
                const int row = rowb + r;
                const int b = row >= Nc ? 1 : 0;
                const int n = row - b * Nc;
                dst[(((long)b * Hc + h) * Nc + n) * DKc + dk] =
                    __float2bfloat16(acc[mt][nt][r]);
            }
        }
    }
}

// ---------------------------------------------------------------------------
// MFMA bf16 NT narrow GEMM core (validated): acc = A(128,K) @ Bt(64,K)^T.
// ---------------------------------------------------------------------------
struct N64Acc { f32x4 acc[2][4]; };

template <typename DUMMY = void>
DEVINL void n64_core(const bf16* A, const bf16* Bt, int K,
                     unsigned short* Asm, unsigned short* Bsm, N64Acc& R)
{
    const int tid  = threadIdx.x;
    const int wave = tid >> 6;
    const int lane = tid & 63;
    const int q    = lane >> 4;
    const int ln   = lane & 15;

    const int sr = tid >> 3, k8 = tid & 7;
    const bf16* pa[4];
    const bf16* pb[2];
    int wa[4], wb[2];
#pragma unroll
    for (int i = 0; i < 4; ++i) {
        pa[i] = A + (long)(sr + i * 32) * K + k8 * 8;
        wa[i] = (sr + i * 32) * 72 + k8 * 8;
    }
#pragma unroll
    for (int i = 0; i < 2; ++i) {
        pb[i] = Bt + (long)(sr + i * 32) * K + k8 * 8;
        wb[i] = (sr + i * 32) * 72 + k8 * 8;
    }

#pragma unroll
    for (int i = 0; i < 2; ++i)
#pragma unroll
        for (int j = 0; j < 4; ++j)
            R.acc[i][j] = (f32x4){0.f, 0.f, 0.f, 0.f};

    for (int k0 = 0; k0 < K; k0 += 64) {
        uint4 va[4], vb[2];
#pragma unroll
        for (int i = 0; i < 4; ++i) va[i] = *(const uint4*)(pa[i] + k0);
#pragma unroll
        for (int i = 0; i < 2; ++i) vb[i] = *(const uint4*)(pb[i] + k0);
        __syncthreads();
#pragma unroll
        for (int i = 0; i < 4; ++i) *(uint4*)&Asm[wa[i]] = va[i];
#pragma unroll
        for (int i = 0; i < 2; ++i) *(uint4*)&Bsm[wb[i]] = vb[i];
        __syncthreads();

#pragma unroll
        for (int kc = 0; kc < 2; ++kc) {
            short8 af[2], bfr[4];
#pragma unroll
            for (int mt = 0; mt < 2; ++mt) {
                int m = wave * 32 + mt * 16 + ln;
                af[mt] = *(const short8*)&Asm[m * 72 + kc * 32 + q * 8];
            }
#pragma unroll
            for (int nt = 0; nt < 4; ++nt) {
                int n = nt * 16 + ln;
                bfr[nt] = *(const short8*)&Bsm[n * 72 + kc * 32 + q * 8];
            }
#pragma unroll
            for (int mt = 0; mt < 2; ++mt)
#pragma unroll
                for (int nt = 0; nt < 4; ++nt)
                    R.acc[mt][nt] = __builtin_amdgcn_mfma_f32_16x16x32_bf16(
                        af[mt], bfr[nt], R.acc[mt][nt], 0, 0, 0);
        }
    }
}

// ---------------------------------------------------------------------------
// Merged pair launch:
//   z <  16: transport = A2 @ v2t -> written TRANSPOSED (64 x Nc) straight to
//            trt via an LDS transpose in the epilogue (kills the separate
//            transpose launch + trb round trip).
//   z >= 16: y_base = A @ v1t -> normal (Nc x 64) write to yb1.
// ---------------------------------------------------------------------------
__global__ __launch_bounds__(256) void gemm_n64_pair(
    const bf16* __restrict__ A0g, const bf16* __restrict__ B0g, bf16* __restrict__ C0tg,
    const bf16* __restrict__ A1g, const bf16* __restrict__ B1g, bf16* __restrict__ C1g,
    int M, int K, long sA, long sB, long sC)
{
    __shared__ unsigned short Asm[128 * 72];
    __shared__ unsigned short Bsm[64 * 72];

    const int zz = blockIdx.z & 15;
    const int second = blockIdx.z >> 4;
    const bf16* A  = (second ? A1g : A0g) + (long)zz * sA + (long)(blockIdx.y * 128) * K;
    const bf16* Bt = (second ? B1g : B0g) + (long)zz * sB;

    N64Acc R;
    n64_core(A, Bt, K, Asm, Bsm, R);

    const int tid = threadIdx.x;
    const int wave = tid >> 6, lane = tid & 63, q = lane >> 4, ln = lane & 15;

    if (second) {
        bf16* C = C1g + (long)zz * sC;
#pragma unroll
        for (int mt = 0; mt < 2; ++mt) {
#pragma unroll
            for (int nt = 0; nt < 4; ++nt) {
                const int col  = nt * 16 + ln;
                const int rowb = blockIdx.y * 128 + wave * 32 + mt * 16 + q * 4;
#pragma unroll
                for (int r = 0; r < 4; ++r)
                    C[(long)(rowb + r) * 64 + col] = __float2bfloat16(R.acc[mt][nt][r]);
            }
        }
    } else {
        // stage C tile into Asm as [dk][n] (stride 136 -> 16B-aligned rows)
        __syncthreads();   // all waves done reading Asm from the K loop
#pragma unroll
        for (int mt = 0; mt < 2; ++mt) {
#pragma unroll
            for (int nt = 0; nt < 4; ++nt) {
                const int col = nt * 16 + ln;                 // dk
                const int rwb = wave * 32 + mt * 16 + q * 4;  // n within tile
#pragma unroll
                for (int r = 0; r < 4; ++r)
                    *(bf16*)&Asm[col * 136 + rwb + r] = __float2bfloat16(R.acc[mt][nt][r]);
            }
        }
        __syncthreads();
        bf16* Ct = C0tg + (long)zz * sC;
        const int dk  = tid >> 2;
        const int nc0 = (tid & 3) * 32;
        const int gn0 = blockIdx.y * 128;
#pragma unroll
        for (int c8 = 0; c8 < 4; ++c8) {
            uint4 v = *(const uint4*)&Asm[dk * 136 + nc0 + c8 * 8];
            *(uint4*)&Ct[(long)dk * Nc + gn0 + nc0 + c8 * 8] = v;
        }
    }
}

// y_chain GEMM with fused combine + permute (validated rounds 9-10).
__global__ __launch_bounds__(256) void gemm_n64_combine(
    const bf16* __restrict__ A1b, const bf16* __restrict__ trt,
    const bf16* __restrict__ yb1, const float* __restrict__ smallf,
    bf16* __restrict__ yc, int M, int K, long sA, long sB)
{
    __shared__ unsigned short Asm[128 * 72];
    __shared__ unsigned short Bsm[64 * 72];

    const int bh = blockIdx.z;
    const bf16* A  = A1b + (long)bh * sA + (long)(blockIdx.y * 128) * K;
    const bf16* Bt = trt + (long)bh * sB;

    N64Acc R;
    n64_core(A, Bt, K, Asm, Bsm, R);

    const float w = sigf(smallf[180]);
    const int b = bh >> 3, h = bh & 7;
    const long yb1base = (long)bh * Nc * DKc;

    const int tid = threadIdx.x;
    const int wave = tid >> 6, lane = tid & 63, q = lane >> 4, ln = lane & 15;
#pragma unroll
    for (int mt = 0; mt < 2; ++mt) {
#pragma unroll
        for (int nt = 0; nt < 4; ++nt) {
            const int col  = nt * 16 + ln;
            const int rowb = blockIdx.y * 128 + wave * 32 + mt * 16 + q * 4;
#pragma unroll
            for (int r = 0; r < 4; ++r) {
                const int n = rowb + r;
                const float base = __bfloat162float(yb1[yb1base + (long)n * 64 + col]);
                yc[((long)(b * Nc + n)) * Dc + h * DKc + col] =
                    __float2bfloat16(base + w * R.acc[mt][nt][r]);
            }
        }
    }
}

// ---------------------------------------------------------------------------
// Row softmax over width 768 (validated; used for A1/A2 only now).
// ---------------------------------------------------------------------------
template <typename TO>
__global__ __launch_bounds__(256) void softmax_rows(const float* src, TO* dst)
{
    __shared__ float red[4];
    const long row = blockIdx.x;
    const float* s = src + row * Nc;
    TO* d = dst + row * Nc;
    const int tid = threadIdx.x;

    float v[3];
    float m = -1e30f;
#pragma unroll
    for (int i = 0; i < 3; ++i) { v[i] = s[tid + i * 256]; m = fmaxf(m, v[i]); }

#pragma unroll
    for (int off = 32; off > 0; off >>= 1) m = fmaxf(m, __shfl_down(m, off, 64));
    if ((tid & 63) == 0) red[tid >> 6] = m;
    __syncthreads();
    if (tid == 0) {
        float mm = red[0];
        for (int w = 1; w < 4; ++w) mm = fmaxf(mm, red[w]);
        red[0] = mm;
    }
    __syncthreads();
    m = red[0];
    __syncthreads();

    float e[3];
    float sum = 0.f;
#pragma unroll
    for (int i = 0; i < 3; ++i) { e[i] = __expf(v[i] - m); sum += e[i]; }
#pragma unroll
    for (int off = 32; off > 0; off >>= 1) sum += __shfl_down(sum, off, 64);
    if ((tid & 63) == 0) red[tid >> 6] = sum;
    __syncthreads();
    if (tid == 0) red[0] = red[0] + red[1] + red[2] + red[3];
    __syncthreads();
    const float inv = 1.f / fmaxf(red[0], 1e-30f);
#pragma unroll
    for (int i = 0; i < 3; ++i) stf(d, tid + i * 256, e[i] * inv);
}

// ---------------------------------------------------------------------------
// FUSED gates + Smix + row-softmax -> A (bf16), one kernel.
// Block = 2 rows (row = 2 waves), 6 elems/thread strided by 128 so lanes stay
// coalesced and the row reduction is wave-local (+1 tiny LDS combine).
// Gate math = validated round-8 scalar body (fast div, sigmoid-form gelu).
// Output A goes into the dead Smix region (NOT S1 — S1 is still being read).
// ---------------------------------------------------------------------------
__global__ __launch_bounds__(256) void gates_smix_softmax(
    const float* __restrict__ S1g, const float* __restrict__ S2g,
    const bf16* __restrict__ Crg, const bf16* __restrict__ Clg,
    bf16* __restrict__ Aout, const float* __restrict__ smallf)
{
    __shared__ float t1t[768][3], t2t[768][3];   // 2 cols + pad (3 coprime 32)
    __shared__ float cs[192];
    __shared__ float red[2][2];

    const long mat = (long)blockIdx.y * (long)Nc * Nc;
    const float* S1 = S1g + mat;
    const float* S2 = S2g + mat;
    const unsigned short* Cr = (const unsigned short*)Crg + mat;
    const unsigned short* Cl = (const unsigned short*)Clg + mat;
    bf16* A = Aout + mat;

    const int tid = threadIdx.x;
    if (tid < 192) cs[tid] = smallf[tid];

    const int n0 = blockIdx.x * 2;
    {   // stage transposed 768x2 tiles of S1/S2
        const int c = tid & 1, rr = tid >> 1;    // rr 0..127
#pragma unroll
        for (int i = 0; i < 6; ++i) {
            const int m = i * 128 + rr;
            t1t[m][c] = S1[(long)m * Nc + n0 + c];
            t2t[m][c] = S2[(long)m * Nc + n0 + c];
        }
    }
    __syncthreads();

    const float* cw1 = cs;       const float* cb1 = cs + 96;
    const float* cw2 = cs + 112; const float* cb2 = cs + 176;

    const int wave = tid >> 6, lane = tid & 63;
    const int ty = wave >> 1;       // row within the 2-row group
    const int wh = wave & 1;        // which 64-lane half of the row
    const int n = n0 + ty;
    const long rowbase = (long)n * Nc;
    const int p0 = wh * 64 + lane;  // positions p0 + 128*j

    float out[6];
    float rmax = -1e30f;
#pragma unroll
    for (int j = 0; j < 6; ++j) {
        const int m = p0 + 128 * j;
        const long idx = rowbase + m;
        const float s1 = S1[idx], s2 = S2[idx];
        const float s1t = t1t[m][ty], s2t = t2t[m][ty];
        const float cr = __uint_as_float(((unsigned)Cr[idx]) << 16);
        const float cl = __uint_as_float(((unsigned)Cl[idx]) << 16);

        const float feat[6] = {s1, s2, s1t, s2t, cr, cl};
        float g[4];
#pragma unroll
        for (int o = 0; o < 4; ++o) g[o] = cb2[o];
#pragma unroll
        for (int u = 0; u < 16; ++u) {
            float h = cb1[u];
#pragma unroll
            for (int c = 0; c < 6; ++c) h = fmaf(feat[c], cw1[u * 6 + c], h);
            const float hh = h * h;
            const float z2 = h * fmaf(hh, -0.0713548162f, -1.5957691216f);
            const float e = __expf(z2);
            const float hid = h * __fdividef(1.f, 1.f + e);
#pragma unroll
            for (int o = 0; o < 4; ++o) g[o] = fmaf(hid, cw2[o * 16 + u], g[o]);
        }
        const float ga = sigf(g[0]);
        const float go = sigf(g[1]);
        const float gn = sigf(g[2]);
        const float gc = sigf(g[3]);
        const float mx = fmaxf(s1, s2);
        const float lae = mx + __logf(1.f + __expf(-fabsf(s1 - s2)));
        out[j] = s1 + ga * s2 + go * (lae - s1) - gn * (BETA_NOT * s2) + gc * cr;
        rmax = fmaxf(rmax, out[j]);
    }

    // row softmax: wave reduce + 2-wave combine
#pragma unroll
    for (int off = 32; off > 0; off >>= 1)
        rmax = fmaxf(rmax, __shfl_xor(rmax, off, 64));
    if (lane == 0) red[ty][wh] = rmax;
    __syncthreads();
    rmax = fmaxf(red[ty][0], red[ty][1]);

    float sum = 0.f;
#pragma unroll
    for (int j = 0; j < 6; ++j) { out[j] = __expf(out[j] - rmax); sum += out[j]; }
#pragma unroll
    for (int off = 32; off > 0; off >>= 1) sum += __shfl_xor(sum, off, 64);
    __syncthreads();                       // everyone has read red (max phase)
    if (lane == 0) red[ty][wh] = sum;
    __syncthreads();
    const float inv = 1.f / fmaxf(red[ty][0] + red[ty][1], 1e-30f);

#pragma unroll
    for (int j = 0; j < 6; ++j)
        A[rowbase + p0 + 128 * j] = __float2bfloat16(out[j] * inv);
}

// ---------------------------------------------------------------------------
// Final projection via MFMA (validated rounds 7-10).
// ---------------------------------------------------------------------------
__global__ __launch_bounds__(256) void proj_mfma(
    const bf16* __restrict__ yc, const bf16* __restrict__ pwt,
    const void* __restrict__ xraw, void* __restrict__ out)
{
    constexpr int K = Dc;  // 512
    constexpr int N = Dc;  // 512
    __shared__ unsigned short Asm[128 * 32];
    __shared__ unsigned short Bsm[128 * 32];
    __shared__ int is32s;

    const int tid  = threadIdx.x;
    if (tid == 0) is32s = sniff_is_fp32(xraw);
    const int wv   = tid >> 6;
    const int lane = tid & 63;
    const int q    = lane >> 4;
    const int ln   = lane & 15;
    const int wm   = wv & 1;
    const int wn   = wv >> 1;

    const bf16* A  = yc  + (long)(blockIdx.y * 128) * K;
    const bf16* Bt = pwt + (long)(blockIdx.x * 128) * K;

    const int sr = lane >> 2, sc = lane & 3;
    const bf16* gA0 = A  + (long)(wv * 32 + sr)      * K + sc * 8;
    const bf16* gA1 = A  + (long)(wv * 32 + 16 + sr) * K + sc * 8;
    const bf16* gB0 = Bt + (long)(wv * 32 + sr)      * K + sc * 8;
    const bf16* gB1 = Bt + (long)(wv * 32 + 16 + sr) * K + sc * 8;
    unsigned short* lA0 = &Asm[(wv * 32)      * 32];
    unsigned short* lA1 = &Asm[(wv * 32 + 16) * 32];
    unsigned short* lB0 = &Bsm[(wv * 32)      * 32];
    unsigned short* lB1 = &Bsm[(wv * 32 + 16) * 32];

    f32x4 acc[4][4];
#pragma unroll
    for (int i = 0; i < 4; ++i)
#pragma unroll
        for (int j = 0; j < 4; ++j)
            acc[i][j] = (f32x4){0.f, 0.f, 0.f, 0.f};

    for (int k0 = 0; k0 < K; k0 += 32) {
        __syncthreads();
        gl_lds16(gA0 + k0, lA0);
        gl_lds16(gA1 + k0, lA1);
        gl_lds16(gB0 + k0, lB0);
        gl_lds16(gB1 + k0, lB1);
        __syncthreads();

        short8 af[4], bfr[4];
#pragma unroll
        for (int mt = 0; mt < 4; ++mt) {
            int m = wm * 64 + mt * 16 + ln;
            af[mt] = *(const short8*)&Asm[m * 32 + q * 8];
        }
#pragma unroll
        for (int nt = 0; nt < 4; ++nt) {
            int n = wn * 64 + nt * 16 + ln;
            bfr[nt] = *(const short8*)&Bsm[n * 32 + q * 8];
        }
#pragma unroll
        for (int mt = 0; mt < 4; ++mt)
#pragma unroll
            for (int nt = 0; nt < 4; ++nt)
                acc[mt][nt] = __builtin_amdgcn_mfma_f32_16x16x32_bf16(
                    af[mt], bfr[nt], acc[mt][nt], 0, 0, 0);
    }

    const int is32 = is32s;
#pragma unroll
    for (int mt = 0; mt < 4; ++mt) {
#pragma unroll
        for (int nt = 0; nt < 4; ++nt) {
            const int col = blockIdx.x * 128 + wn * 64 + nt * 16 + ln;
            const int rowb = blockIdx.y * 128 + wm * 64 + mt * 16 + q * 4;
#pragma unroll
            for (int r = 0; r < 4; ++r) {
                const long o = (long)(rowb + r) * N + col;
                if (is32) ((float*)out)[o] = acc[mt][nt][r];
                else      ((bf16*)out)[o] = __float2bfloat16(acc[mt][nt][r]);
            }
        }
    }
}

// ---------------------------------------------------------------------------
extern "C" void kernel_launch(void* const* d_in, const int* in_sizes, int n_in,
                              void* d_out, int out_size, void* d_ws, size_t ws_size,
                              hipStream_t stream)
{
    const size_t HD   = (size_t)BHc * Nc * DKc;   // 786432
    const size_t HDh  = HD / 2;                   // float-slots for HD bf16
    const size_t MAT  = (size_t)Nc * Nc;          // 589824
    const size_t MATS = (size_t)BHc * MAT;        // 9437184
    const long   HSTR = (long)Nc * DKc;           // 49152 per-head stride

    float* ws = (float*)d_ws;
    size_t off = 0;
    auto alloc = [&](size_t n) { float* p = ws + off; off += n; return p; };

    bf16* xb  = (bf16*)alloc(HDh);
    bf16* w1b = (bf16*)alloc(HDh);   // w1b/w2b adjacent -> merged transpose
    bf16* w2b = (bf16*)alloc(HDh);
    bf16* w1t = (bf16*)alloc(HDh);
    bf16* w2t = (bf16*)alloc(HDh);
    bf16* pwb = (bf16*)alloc((size_t)Dc * Dc / 2);
    bf16* pwt = (bf16*)alloc((size_t)Dc * Dc / 2);
    float* smallf = alloc(192);
    // q1|q2 and k1|k2 adjacent -> single merged S-GEMM launch (32 heads)
    bf16* q1b = (bf16*)alloc(HDh); bf16* q2b = (bf16*)alloc(HDh);
    bf16* k1b = (bf16*)alloc(HDh); bf16* k2b = (bf16*)alloc(HDh);
    bf16* v1b = (bf16*)alloc(HDh); bf16* v2b = (bf16*)alloc(HDh);  // adjacent
    bf16* v1t = (bf16*)alloc(HDh); bf16* v2t = (bf16*)alloc(HDh);  // adjacent
    bf16* trt = (bf16*)alloc(HDh);
    float* S1   = alloc(MATS);       // S1/S2 adjacent -> merged softmax + S-GEMM
    float* S2   = alloc(MATS);
    float* Smix = alloc(MATS);       // region reused: A1tb|A2tb, then A
    bf16* A1b = (bf16*)alloc(MATS / 2);  // A1b/A2b adjacent
    bf16* A2b = (bf16*)alloc(MATS / 2);
    bf16* Crb = (bf16*)alloc(MATS / 2);  // Crb/Clb adjacent (merged launch)
    bf16* Clb = (bf16*)alloc(MATS / 2);
    bf16* yb1 = (bf16*)alloc(HDh);
    bf16* yc  = (bf16*)alloc(HDh);

    // aliases into the Smix region (S1/S2 stay read-only after step 2)
    bf16* A1tb = (bf16*)Smix;            // live: steps 3-4
    bf16* A2tb = ((bf16*)Smix) + MATS;
    bf16* Ab   = (bf16*)Smix;            // live: steps 5-7 (A1tb/A2tb dead)

    const size_t NEED_BYTES = off * sizeof(float);
    if (ws_size < NEED_BYTES) {
        fill_sentinel<<<dim3(3072), 256, 0, stream>>>((unsigned short*)d_out);
        return;
    }

    // 0. normalize inputs
    convert_all<<<dim3(3072), 256, 0, stream>>>(
        d_in[0], d_in[1], d_in[2], d_in[3], d_in[4], d_in[5], d_in[6], d_in[7],
        d_in[8], xb, w1b, w2b, pwb, smallf);

    // 1. merged W transposes; pw transpose; merged QKV; merged v transposes
    transpose_bf16<<<dim3(24, 8, 2), 256, 0, stream>>>(
        (const unsigned short*)w1b, (unsigned short*)w1t, Dc, 3 * Dc, (long)HD, (long)HD);
    transpose_bf16<<<dim3(8, 8, 1), 256, 0, stream>>>(
        (const unsigned short*)pwb, (unsigned short*)pwt, Dc, Dc, 0, 0);
    qkv_mfma<<<dim3(12, 12, 2), 256, 0, stream>>>(
        xb, w1t, w2t, q1b, k1b, v1b, q2b, k2b, v2b);
    transpose_bf16<<<dim3(1, 12, 2 * BHc), 256, 0, stream>>>(
        (const unsigned short*)v1b, (unsigned short*)v1t, Nc, DKc, HSTR, HSTR);

    // 2. S = scale * q @ k^T — single 32-batch launch
    gemm_nt_mfma<0, float><<<dim3(6, 6, 2 * BHc), 256, 0, stream>>>(
        q1b, k1b, S1, Nc, Nc, DKc, HSTR, HSTR, (long)MAT, SCALE);

    // 3. merged softmax S1|S2 -> A1b|A2b; merged transposes -> A1tb|A2tb
    softmax_rows<bf16><<<2 * BHc * Nc, 256, 0, stream>>>(S1, A1b);
    transpose_bf16<<<dim3(12, 12, 2 * BHc), 256, 0, stream>>>(
        (const unsigned short*)A1b, (unsigned short*)A1tb, Nc, Nc, (long)MAT, (long)MAT);

    // 4. Cr|Cl in ONE 32-batch launch (Bt batch = z^16; C regions adjacent)
    gemm_nt_mfma<1, bf16, 1><<<dim3(6, 6, 2 * BHc), 256, 0, stream>>>(
        A1b, A1tb, Crb, Nc, Nc, Nc, (long)MAT, (long)MAT, (long)MAT, 1.f);

    // 5. FUSED gates + Smix + softmax -> A (into Smix region)
    gates_smix_softmax<<<dim3(Nc / 2, BHc), 256, 0, stream>>>(
        S1, S2, Crb, Clb, Ab, smallf);

    // 6. merged: transport = A2 @ v2 -> trt (transposed epilogue, z<16)
    //            y_base   = A  @ v1 -> yb1 (z>=16)
    gemm_n64_pair<<<dim3(1, 6, 2 * BHc), 256, 0, stream>>>(
        A2b, v2t, trt, Ab, v1t, yb1, Nc, Nc, (long)MAT, HSTR, HSTR);

    // 7. y_chain GEMM with fused combine + permute -> yc
    gemm_n64_combine<<<dim3(1, 6, BHc), 256, 0, stream>>>(
        A1b, trt, yb1, smallf, yc, Nc, Nc, (long)MAT, HSTR);

    // 8. proj via MFMA + dtype-aware store
    proj_mfma<<<dim3(4, 12, 1), 256, 0, stream>>>(yc, pwt, d_in[0], d_out);
}

// Round 12
// 461.537 us; speedup vs baseline: 1.0810x; 1.0810x over previous
//
#include <hip/hip_runtime.h>
#include <hip/hip_bf16.h>
#include <math.h>

typedef __hip_bfloat16 bf16;
typedef __attribute__((ext_vector_type(8))) short short8;   // 8 bf16 (4 VGPRs)
typedef __attribute__((ext_vector_type(4))) float f32x4;
#define DEVINL __device__ __forceinline__

constexpr int Bc  = 2;
constexpr int Nc  = 768;
constexpr int Dc  = 512;
constexpr int Hc  = 8;
constexpr int DKc = 64;
constexpr int BHc = Bc * Hc;
constexpr float SCALE    = 0.125f;   // 1/sqrt(64)
constexpr float EPSF     = 1e-6f;
constexpr float BETA_NOT = 0.5f;

DEVINL float ldf(const float* p, long i) { return p[i]; }
DEVINL float ldf(const bf16* p, long i) { return __bfloat162float(p[i]); }
DEVINL void stf(float* p, long i, float v) { p[i] = v; }
DEVINL void stf(bf16* p, long i, float v) { p[i] = __float2bfloat16(v); }

DEVINL float sigf(float x) { return __fdividef(1.f, 1.f + __expf(-x)); }

// async global->LDS, 16B per lane; LDS dest = wave-uniform base + lane*16.
DEVINL void gl_lds16(const void* g, void* l) {
    __builtin_amdgcn_global_load_lds(
        (const __attribute__((address_space(1))) void*)g,
        (__attribute__((address_space(3))) void*)l, 16, 0, 0);
}

// ---------------------------------------------------------------------------
// Dtype sniffer — vectorized (validated round 9).
// ---------------------------------------------------------------------------
DEVINL int sniff_is_fp32(const void* xraw) {
    const uint4* p4 = (const uint4*)xraw;
    float mx = 0.f;
#pragma unroll
    for (int j = 0; j < 16; ++j) {
        const uint4 u = p4[j];
        const unsigned w[4] = {u.x, u.y, u.z, u.w};
#pragma unroll
        for (int t = 0; t < 4; ++t) {
            mx = fmaxf(mx, fabsf(__uint_as_float((w[t] & 0xffffu) << 16)));
            mx = fmaxf(mx, fabsf(__uint_as_float(w[t] & 0xffff0000u)));
        }
    }
    return mx > 1000.f ? 1 : 0;
}

DEVINL float cvt_elem(const void* s, long j, int is32) {
    return is32 ? ((const float*)s)[j]
                : __bfloat162float(((const bf16*)s)[j]);
}

__global__ __launch_bounds__(256) void convert_all(
    const void* x, const void* w1, const void* w2, const void* pw,
    const void* c1w, const void* c1b, const void* c2w, const void* c2b,
    const void* ch,
    bf16* xb, bf16* w1b, bf16* w2b, bf16* pwb, float* smallf)
{
    __shared__ int is32s;
    if (threadIdx.x == 0) is32s = sniff_is_fp32(x);
    __syncthreads();
    const int is32 = is32s;
    const long i = (long)blockIdx.x * 256 + threadIdx.x;
    if (i < (long)Bc * Nc * Dc) {
        xb[i]  = __float2bfloat16(cvt_elem(x,  i, is32));
        w1b[i] = __float2bfloat16(cvt_elem(w1, i, is32));
        w2b[i] = __float2bfloat16(cvt_elem(w2, i, is32));
    }
    if (i < (long)Dc * Dc) pwb[i] = __float2bfloat16(cvt_elem(pw, i, is32));
    if (i < 96)       smallf[i] = cvt_elem(c1w, i,        is32);
    else if (i < 112) smallf[i] = cvt_elem(c1b, i - 96,   is32);
    else if (i < 176) smallf[i] = cvt_elem(c2w, i - 112,  is32);
    else if (i < 180) smallf[i] = cvt_elem(c2b, i - 176,  is32);
    else if (i == 180) smallf[180] = cvt_elem(ch, 0, is32);
}

__global__ __launch_bounds__(256) void fill_sentinel(unsigned short* o) {
    const long i = (long)blockIdx.x * 256 + threadIdx.x;
    if (i < (long)Bc * Nc * Dc) o[i] = 0x40E0;  // bf16 7.0
}

// ---------------------------------------------------------------------------
// Generic bf16 transpose, 64x64 tiles: dst[c][r] = src[r][c]; src is (R,C).
// ---------------------------------------------------------------------------
__global__ __launch_bounds__(256) void transpose_bf16(
    const unsigned short* __restrict__ src, unsigned short* __restrict__ dst,
    int R, int C, long sS, long sD)
{
    __shared__ unsigned short tile[64][68];
    const unsigned short* s = src + (long)blockIdx.z * sS;
    unsigned short* d = dst + (long)blockIdx.z * sD;
    const int r0 = blockIdx.y * 64, c0 = blockIdx.x * 64;
    const int t = threadIdx.x;
    const int lr = t >> 4, lc4 = (t & 15) * 4;
#pragma unroll
    for (int i = 0; i < 4; ++i) {
        int r = lr + i * 16;
        *(uint2*)&tile[r][lc4] = *(const uint2*)&s[(long)(r0 + r) * C + c0 + lc4];
    }
    __syncthreads();
#pragma unroll
    for (int i = 0; i < 4; ++i) {
        int r = lr + i * 16;
        unsigned short v[4];
#pragma unroll
        for (int j = 0; j < 4; ++j) v[j] = tile[lc4 + j][r];
        *(uint2*)&d[(long)(c0 + r) * R + r0 + lc4] = *(uint2*)v;
    }
}

// ---------------------------------------------------------------------------
// MFMA bf16 NT GEMM with global_load_lds staging (validated rounds 6-11):
// C = A(M,K) @ Bt(N,K)^T. 128x128 tile, BK=32.
// XORB: B batch index = z^16 (merged Cr/Cl trick; adjacency-dependent).
// ---------------------------------------------------------------------------
template <int EPI, typename TC, int XORB = 0>
__global__ __launch_bounds__(256) void gemm_nt_mfma(
    const bf16* __restrict__ Ag, const bf16* __restrict__ Btg,
    TC* __restrict__ Cg, int M, int N, int K,
    long sA, long sB, long sC, float alpha)
{
    __shared__ unsigned short Asm[128 * 32];
    __shared__ unsigned short Bsm[128 * 32];

    const int tid  = threadIdx.x;
    const int wv   = tid >> 6;
    const int lane = tid & 63;
    const int q    = lane >> 4;
    const int ln   = lane & 15;
    const int wm   = wv & 1;
    const int wn   = wv >> 1;

    const int zb = XORB ? ((int)blockIdx.z ^ 16) : (int)blockIdx.z;
    const bf16* A  = Ag  + (long)blockIdx.z * sA + (long)(blockIdx.y * 128) * K;
    const bf16* Bt = Btg + (long)zb * sB + (long)(blockIdx.x * 128) * K;
    TC*         C  = Cg  + (long)blockIdx.z * sC;

    const int sr = lane >> 2, sc = lane & 3;
    const bf16* gA0 = A  + (long)(wv * 32 + sr)      * K + sc * 8;
    const bf16* gA1 = A  + (long)(wv * 32 + 16 + sr) * K + sc * 8;
    const bf16* gB0 = Bt + (long)(wv * 32 + sr)      * K + sc * 8;
    const bf16* gB1 = Bt + (long)(wv * 32 + 16 + sr) * K + sc * 8;
    unsigned short* lA0 = &Asm[(wv * 32)      * 32];
    unsigned short* lA1 = &Asm[(wv * 32 + 16) * 32];
    unsigned short* lB0 = &Bsm[(wv * 32)      * 32];
    unsigned short* lB1 = &Bsm[(wv * 32 + 16) * 32];

    f32x4 acc[4][4];
#pragma unroll
    for (int i = 0; i < 4; ++i)
#pragma unroll
        for (int j = 0; j < 4; ++j)
            acc[i][j] = (f32x4){0.f, 0.f, 0.f, 0.f};

    for (int k0 = 0; k0 < K; k0 += 32) {
        __syncthreads();
        gl_lds16(gA0 + k0, lA0);
        gl_lds16(gA1 + k0, lA1);
        gl_lds16(gB0 + k0, lB0);
        gl_lds16(gB1 + k0, lB1);
        __syncthreads();

        short8 af[4], bfr[4];
#pragma unroll
        for (int mt = 0; mt < 4; ++mt) {
            int m = wm * 64 + mt * 16 + ln;
            af[mt] = *(const short8*)&Asm[m * 32 + q * 8];
        }
#pragma unroll
        for (int nt = 0; nt < 4; ++nt) {
            int n = wn * 64 + nt * 16 + ln;
            bfr[nt] = *(const short8*)&Bsm[n * 32 + q * 8];
        }
#pragma unroll
        for (int mt = 0; mt < 4; ++mt)
#pragma unroll
            for (int nt = 0; nt < 4; ++nt)
                acc[mt][nt] = __builtin_amdgcn_mfma_f32_16x16x32_bf16(
                    af[mt], bfr[nt], acc[mt][nt], 0, 0, 0);
    }

#pragma unroll
    for (int mt = 0; mt < 4; ++mt) {
#pragma unroll
        for (int nt = 0; nt < 4; ++nt) {
            const int col = blockIdx.x * 128 + wn * 64 + nt * 16 + ln;
            const int rowb = blockIdx.y * 128 + wm * 64 + mt * 16 + q * 4;
#pragma unroll
            for (int r = 0; r < 4; ++r) {
                float v = acc[mt][nt][r] * alpha;
                if (EPI == 1) v = __logf(fmaxf(v, 0.f) + EPSF);
                stf(C, (long)(rowb + r) * N + col, v);
            }
        }
    }
}

// ---------------------------------------------------------------------------
// QKV via MFMA, merged sets (validated rounds 6-11).
// ---------------------------------------------------------------------------
__global__ __launch_bounds__(256) void qkv_mfma(
    const bf16* __restrict__ X,
    const bf16* __restrict__ w1t, const bf16* __restrict__ w2t,
    bf16* __restrict__ q1, bf16* __restrict__ k1, bf16* __restrict__ v1,
    bf16* __restrict__ q2, bf16* __restrict__ k2, bf16* __restrict__ v2)
{
    constexpr int K = Dc;  // 512
    __shared__ unsigned short Asm[128 * 32];
    __shared__ unsigned short Bsm[128 * 32];

    const int tid  = threadIdx.x;
    const int wv   = tid >> 6;
    const int lane = tid & 63;
    const int q    = lane >> 4;
    const int ln   = lane & 15;
    const int wm   = wv & 1;
    const int wn   = wv >> 1;
    const int set  = blockIdx.z;

    const bf16* Wt = set ? w2t : w1t;
    bf16* Q  = set ? q2 : q1;
    bf16* Ko = set ? k2 : k1;
    bf16* V  = set ? v2 : v1;

    const bf16* A  = X  + (long)(blockIdx.y * 128) * K;
    const bf16* Bt = Wt + (long)(blockIdx.x * 128) * K;

    const int sr = lane >> 2, sc = lane & 3;
    const bf16* gA0 = A  + (long)(wv * 32 + sr)      * K + sc * 8;
    const bf16* gA1 = A  + (long)(wv * 32 + 16 + sr) * K + sc * 8;
    const bf16* gB0 = Bt + (long)(wv * 32 + sr)      * K + sc * 8;
    const bf16* gB1 = Bt + (long)(wv * 32 + 16 + sr) * K + sc * 8;
    unsigned short* lA0 = &Asm[(wv * 32)      * 32];
    unsigned short* lA1 = &Asm[(wv * 32 + 16) * 32];
    unsigned short* lB0 = &Bsm[(wv * 32)      * 32];
    unsigned short* lB1 = &Bsm[(wv * 32 + 16) * 32];

    f32x4 acc[4][4];
#pragma unroll
    for (int i = 0; i < 4; ++i)
#pragma unroll
        for (int j = 0; j < 4; ++j)
            acc[i][j] = (f32x4){0.f, 0.f, 0.f, 0.f};

    for (int k0 = 0; k0 < K; k0 += 32) {
        __syncthreads();
        gl_lds16(gA0 + k0, lA0);
        gl_lds16(gA1 + k0, lA1);
        gl_lds16(gB0 + k0, lB0);
        gl_lds16(gB1 + k0, lB1);
        __syncthreads();

        short8 af[4], bfr[4];
#pragma unroll
        for (int mt = 0; mt < 4; ++mt) {
            int m = wm * 64 + mt * 16 + ln;
            af[mt] = *(const short8*)&Asm[m * 32 + q * 8];
        }
#pragma unroll
        for (int nt = 0; nt < 4; ++nt) {
            int n = wn * 64 + nt * 16 + ln;
            bfr[nt] = *(const short8*)&Bsm[n * 32 + q * 8];
        }
#pragma unroll
        for (int mt = 0; mt < 4; ++mt)
#pragma unroll
            for (int nt = 0; nt < 4; ++nt)
                acc[mt][nt] = __builtin_amdgcn_mfma_f32_16x16x32_bf16(
                    af[mt], bfr[nt], acc[mt][nt], 0, 0, 0);
    }

#pragma unroll
    for (int mt = 0; mt < 4; ++mt) {
#pragma unroll
        for (int nt = 0; nt < 4; ++nt) {
            const int col  = blockIdx.x * 128 + wn * 64 + nt * 16 + ln;
            const int rowb = blockIdx.y * 128 + wm * 64 + mt * 16 + q * 4;
            const int t = col >> 9;
            const int h = (col >> 6) & 7;
            const int dk = col & 63;
            bf16* dst = (t == 0) ? Q : (t == 1) ? Ko : V;
#pragma unroll
            for (int r = 0; r < 4; ++r) {
                const int row = rowb + r;
                const int b = row >= Nc ? 1 : 0;
                const int n = row - b * Nc;
                dst[(((long)b * Hc + h) * Nc + n) * DKc + dk] =
                    __float2bfloat16(acc[mt][nt][r]);
            }
        }
    }
}

// ---------------------------------------------------------------------------
// MFMA bf16 NT narrow GEMM core (validated): acc = A(128,K) @ Bt(64,K)^T.
// ---------------------------------------------------------------------------
struct N64Acc { f32x4 acc[2][4]; };

template <typename DUMMY = void>
DEVINL void n64_core(const bf16* A, const bf16* Bt, int K,
                     unsigned short* Asm, unsigned short* Bsm, N64Acc& R)
{
    const int tid  = threadIdx.x;
    const int wave = tid >> 6;
    const int lane = tid & 63;
    const int q    = lane >> 4;
    const int ln   = lane & 15;

    const int sr = tid >> 3, k8 = tid & 7;
    const bf16* pa[4];
    const bf16* pb[2];
    int wa[4], wb[2];
#pragma unroll
    for (int i = 0; i < 4; ++i) {
        pa[i] = A + (long)(sr + i * 32) * K + k8 * 8;
        wa[i] = (sr + i * 32) * 72 + k8 * 8;
    }
#pragma unroll
    for (int i = 0; i < 2; ++i) {
        pb[i] = Bt + (long)(sr + i * 32) * K + k8 * 8;
        wb[i] = (sr + i * 32) * 72 + k8 * 8;
    }

#pragma unroll
    for (int i = 0; i < 2; ++i)
#pragma unroll
        for (int j = 0; j < 4; ++j)
            R.acc[i][j] = (f32x4){0.f, 0.f, 0.f, 0.f};

    for (int k0 = 0; k0 < K; k0 += 64) {
        uint4 va[4], vb[2];
#pragma unroll
        for (int i = 0; i < 4; ++i) va[i] = *(const uint4*)(pa[i] + k0);
#pragma unroll
        for (int i = 0; i < 2; ++i) vb[i] = *(const uint4*)(pb[i] + k0);
        __syncthreads();
#pragma unroll
        for (int i = 0; i < 4; ++i) *(uint4*)&Asm[wa[i]] = va[i];
#pragma unroll
        for (int i = 0; i < 2; ++i) *(uint4*)&Bsm[wb[i]] = vb[i];
        __syncthreads();

#pragma unroll
        for (int kc = 0; kc < 2; ++kc) {
            short8 af[2], bfr[4];
#pragma unroll
            for (int mt = 0; mt < 2; ++mt) {
                int m = wave * 32 + mt * 16 + ln;
                af[mt] = *(const short8*)&Asm[m * 72 + kc * 32 + q * 8];
            }
#pragma unroll
            for (int nt = 0; nt < 4; ++nt) {
                int n = nt * 16 + ln;
                bfr[nt] = *(const short8*)&Bsm[n * 72 + kc * 32 + q * 8];
            }
#pragma unroll
            for (int mt = 0; mt < 2; ++mt)
#pragma unroll
                for (int nt = 0; nt < 4; ++nt)
                    R.acc[mt][nt] = __builtin_amdgcn_mfma_f32_16x16x32_bf16(
                        af[mt], bfr[nt], R.acc[mt][nt], 0, 0, 0);
        }
    }
}

// ---------------------------------------------------------------------------
// Merged pair launch (validated round 11):
//   z <  16: transport = A2 @ v2t -> written TRANSPOSED (64 x Nc) straight to
//            trt via an LDS transpose in the epilogue.
//   z >= 16: y_base = A @ v1t -> normal (Nc x 64) write to yb1.
// ---------------------------------------------------------------------------
__global__ __launch_bounds__(256) void gemm_n64_pair(
    const bf16* __restrict__ A0g, const bf16* __restrict__ B0g, bf16* __restrict__ C0tg,
    const bf16* __restrict__ A1g, const bf16* __restrict__ B1g, bf16* __restrict__ C1g,
    int M, int K, long sA, long sB, long sC)
{
    __shared__ unsigned short Asm[128 * 72];
    __shared__ unsigned short Bsm[64 * 72];

    const int zz = blockIdx.z & 15;
    const int second = blockIdx.z >> 4;
    const bf16* A  = (second ? A1g : A0g) + (long)zz * sA + (long)(blockIdx.y * 128) * K;
    const bf16* Bt = (second ? B1g : B0g) + (long)zz * sB;

    N64Acc R;
    n64_core(A, Bt, K, Asm, Bsm, R);

    const int tid = threadIdx.x;
    const int wave = tid >> 6, lane = tid & 63, q = lane >> 4, ln = lane & 15;

    if (second) {
        bf16* C = C1g + (long)zz * sC;
#pragma unroll
        for (int mt = 0; mt < 2; ++mt) {
#pragma unroll
            for (int nt = 0; nt < 4; ++nt) {
                const int col  = nt * 16 + ln;
                const int rowb = blockIdx.y * 128 + wave * 32 + mt * 16 + q * 4;
#pragma unroll
                for (int r = 0; r < 4; ++r)
                    C[(long)(rowb + r) * 64 + col] = __float2bfloat16(R.acc[mt][nt][r]);
            }
        }
    } else {
        // stage C tile into Asm as [dk][n] (stride 136 -> 16B-aligned rows)
        __syncthreads();   // all waves done reading Asm from the K loop
#pragma unroll
        for (int mt = 0; mt < 2; ++mt) {
#pragma unroll
            for (int nt = 0; nt < 4; ++nt) {
                const int col = nt * 16 + ln;                 // dk
                const int rwb = wave * 32 + mt * 16 + q * 4;  // n within tile
#pragma unroll
                for (int r = 0; r < 4; ++r)
                    *(bf16*)&Asm[col * 136 + rwb + r] = __float2bfloat16(R.acc[mt][nt][r]);
            }
        }
        __syncthreads();
        bf16* Ct = C0tg + (long)zz * sC;
        const int dk  = tid >> 2;
        const int nc0 = (tid & 3) * 32;
        const int gn0 = blockIdx.y * 128;
#pragma unroll
        for (int c8 = 0; c8 < 4; ++c8) {
            uint4 v = *(const uint4*)&Asm[dk * 136 + nc0 + c8 * 8];
            *(uint4*)&Ct[(long)dk * Nc + gn0 + nc0 + c8 * 8] = v;
        }
    }
}

// y_chain GEMM with fused combine + permute (validated rounds 9-11).
__global__ __launch_bounds__(256) void gemm_n64_combine(
    const bf16* __restrict__ A1b, const bf16* __restrict__ trt,
    const bf16* __restrict__ yb1, const float* __restrict__ smallf,
    bf16* __restrict__ yc, int M, int K, long sA, long sB)
{
    __shared__ unsigned short Asm[128 * 72];
    __shared__ unsigned short Bsm[64 * 72];

    const int bh = blockIdx.z;
    const bf16* A  = A1b + (long)bh * sA + (long)(blockIdx.y * 128) * K;
    const bf16* Bt = trt + (long)bh * sB;

    N64Acc R;
    n64_core(A, Bt, K, Asm, Bsm, R);

    const float w = sigf(smallf[180]);
    const int b = bh >> 3, h = bh & 7;
    const long yb1base = (long)bh * Nc * DKc;

    const int tid = threadIdx.x;
    const int wave = tid >> 6, lane = tid & 63, q = lane >> 4, ln = lane & 15;
#pragma unroll
    for (int mt = 0; mt < 2; ++mt) {
#pragma unroll
        for (int nt = 0; nt < 4; ++nt) {
            const int col  = nt * 16 + ln;
            const int rowb = blockIdx.y * 128 + wave * 32 + mt * 16 + q * 4;
#pragma unroll
            for (int r = 0; r < 4; ++r) {
                const int n = rowb + r;
                const float base = __bfloat162float(yb1[yb1base + (long)n * 64 + col]);
                yc[((long)(b * Nc + n)) * Dc + h * DKc + col] =
                    __float2bfloat16(base + w * R.acc[mt][nt][r]);
            }
        }
    }
}

// ---------------------------------------------------------------------------
// Row softmax over width 768 (validated).
// ---------------------------------------------------------------------------
template <typename TO>
__global__ __launch_bounds__(256) void softmax_rows(const float* src, TO* dst)
{
    __shared__ float red[4];
    const long row = blockIdx.x;
    const float* s = src + row * Nc;
    TO* d = dst + row * Nc;
    const int tid = threadIdx.x;

    float v[3];
    float m = -1e30f;
#pragma unroll
    for (int i = 0; i < 3; ++i) { v[i] = s[tid + i * 256]; m = fmaxf(m, v[i]); }

#pragma unroll
    for (int off = 32; off > 0; off >>= 1) m = fmaxf(m, __shfl_down(m, off, 64));
    if ((tid & 63) == 0) red[tid >> 6] = m;
    __syncthreads();
    if (tid == 0) {
        float mm = red[0];
        for (int w = 1; w < 4; ++w) mm = fmaxf(mm, red[w]);
        red[0] = mm;
    }
    __syncthreads();
    m = red[0];
    __syncthreads();

    float e[3];
    float sum = 0.f;
#pragma unroll
    for (int i = 0; i < 3; ++i) { e[i] = __expf(v[i] - m); sum += e[i]; }
#pragma unroll
    for (int off = 32; off > 0; off >>= 1) sum += __shfl_down(sum, off, 64);
    if ((tid & 63) == 0) red[tid >> 6] = sum;
    __syncthreads();
    if (tid == 0) red[0] = red[0] + red[1] + red[2] + red[3];
    __syncthreads();
    const float inv = 1.f / fmaxf(red[0], 1e-30f);
#pragma unroll
    for (int i = 0; i < 3; ++i) stf(d, tid + i * 256, e[i] * inv);
}

// ---------------------------------------------------------------------------
// Gate network + Smix — round-9 2 elem/thread scalar body (measured 138 µs,
// VGPR 32, occ 82% across three rounds — the validated floor). Round-11
// fusion regressed via VGPR 116 + uncoalesced staging; reverted.
// ---------------------------------------------------------------------------
__global__ __launch_bounds__(256) void gates_smix(
    const float* __restrict__ S1g, const float* __restrict__ S2g,
    const bf16* __restrict__ Crg, const bf16* __restrict__ Clg,
    float* __restrict__ Smixg, const float* __restrict__ smallf)
{
    __shared__ float t1t[32][17], t2t[32][17];
    __shared__ float cs[192];

    const long mat = (long)blockIdx.z * Nc * Nc;
    const float* S1 = S1g + mat;
    const float* S2 = S2g + mat;
    const unsigned short* Cr = (const unsigned short*)Crg + mat;
    const unsigned short* Cl = (const unsigned short*)Clg + mat;
    float* Smix = Smixg + mat;

    const int tid = threadIdx.x;
    if (tid < 192) cs[tid] = smallf[tid];

    const int n0 = blockIdx.y * 16, m0 = blockIdx.x * 32;
    {   // transposed tiles: S[m0..m0+31][n0..n0+15], coalesced float2 loads
        const int r = tid >> 3, c2 = (tid & 7) * 2;
        const float2 a = *(const float2*)&S1[(long)(m0 + r) * Nc + n0 + c2];
        const float2 b = *(const float2*)&S2[(long)(m0 + r) * Nc + n0 + c2];
        t1t[r][c2] = a.x; t1t[r][c2 + 1] = a.y;
        t2t[r][c2] = b.x; t2t[r][c2 + 1] = b.y;
    }
    __syncthreads();

    const float* cw1 = cs;       const float* cb1 = cs + 96;
    const float* cw2 = cs + 112; const float* cb2 = cs + 176;

    const int tx = tid & 15, ty = tid >> 4;
    const int n = n0 + ty;
    const long idx = (long)n * Nc + m0 + tx * 2;

    const float2 s1v = *(const float2*)&S1[idx];
    const float2 s2v = *(const float2*)&S2[idx];
    const unsigned cru = *(const unsigned*)&Cr[idx];   // idx even -> 4B aligned
    const unsigned clu = *(const unsigned*)&Cl[idx];

    float s1a[2] = {s1v.x, s1v.y};
    float s2a[2] = {s2v.x, s2v.y};
    float cra[2] = {__uint_as_float((cru & 0xffffu) << 16),
                    __uint_as_float(cru & 0xffff0000u)};
    float cla[2] = {__uint_as_float((clu & 0xffffu) << 16),
                    __uint_as_float(clu & 0xffff0000u)};
    float s1t[2], s2t[2];
#pragma unroll
    for (int j = 0; j < 2; ++j) {
        s1t[j] = t1t[tx * 2 + j][ty];
        s2t[j] = t2t[tx * 2 + j][ty];
    }

    float g[4][2];
#pragma unroll
    for (int o = 0; o < 4; ++o)
#pragma unroll
        for (int j = 0; j < 2; ++j) g[o][j] = cb2[o];

#pragma unroll
    for (int u = 0; u < 16; ++u) {
        const float wf0 = cw1[u * 6 + 0], wf1 = cw1[u * 6 + 1], wf2 = cw1[u * 6 + 2];
        const float wf3 = cw1[u * 6 + 3], wf4 = cw1[u * 6 + 4], wf5 = cw1[u * 6 + 5];
        const float bu = cb1[u];
        float hid[2];
#pragma unroll
        for (int j = 0; j < 2; ++j) {
            float h = bu;
            h = fmaf(s1a[j], wf0, h);
            h = fmaf(s2a[j], wf1, h);
            h = fmaf(s1t[j], wf2, h);
            h = fmaf(s2t[j], wf3, h);
            h = fmaf(cra[j], wf4, h);
            h = fmaf(cla[j], wf5, h);
            const float hh = h * h;
            const float z2 = h * fmaf(hh, -0.0713548162f, -1.5957691216f);
            const float e = __expf(z2);
            hid[j] = h * __fdividef(1.f, 1.f + e);
        }
#pragma unroll
        for (int o = 0; o < 4; ++o) {
            const float w2o = cw2[o * 16 + u];
#pragma unroll
            for (int j = 0; j < 2; ++j) g[o][j] = fmaf(hid[j], w2o, g[o][j]);
        }
    }

    float out[2];
#pragma unroll
    for (int j = 0; j < 2; ++j) {
        const float ga = sigf(g[0][j]);
        const float go = sigf(g[1][j]);
        const float gn = sigf(g[2][j]);
        const float gc = sigf(g[3][j]);
        const float s1 = s1a[j], s2 = s2a[j];
        const float mx = fmaxf(s1, s2);
        const float lae = mx + __logf(1.f + __expf(-fabsf(s1 - s2)));
        out[j] = s1 + ga * s2 + go * (lae - s1) - gn * (BETA_NOT * s2) + gc * cra[j];
    }
    *(float2*)&Smix[idx] = (float2){out[0], out[1]};
}

// ---------------------------------------------------------------------------
// Final projection via MFMA (validated rounds 7-11).
// ---------------------------------------------------------------------------
__global__ __launch_bounds__(256) void proj_mfma(
    const bf16* __restrict__ yc, const bf16* __restrict__ pwt,
    const void* __restrict__ xraw, void* __restrict__ out)
{
    constexpr int K = Dc;  // 512
    constexpr int N = Dc;  // 512
    __shared__ unsigned short Asm[128 * 32];
    __shared__ unsigned short Bsm[128 * 32];
    __shared__ int is32s;

    const int tid  = threadIdx.x;
    if (tid == 0) is32s = sniff_is_fp32(xraw);
    const int wv   = tid >> 6;
    const int lane = tid & 63;
    const int q    = lane >> 4;
    const int ln   = lane & 15;
    const int wm   = wv & 1;
    const int wn   = wv >> 1;

    const bf16* A  = yc  + (long)(blockIdx.y * 128) * K;
    const bf16* Bt = pwt + (long)(blockIdx.x * 128) * K;

    const int sr = lane >> 2, sc = lane & 3;
    const bf16* gA0 = A  + (long)(wv * 32 + sr)      * K + sc * 8;
    const bf16* gA1 = A  + (long)(wv * 32 + 16 + sr) * K + sc * 8;
    const bf16* gB0 = Bt + (long)(wv * 32 + sr)      * K + sc * 8;
    const bf16* gB1 = Bt + (long)(wv * 32 + 16 + sr) * K + sc * 8;
    unsigned short* lA0 = &Asm[(wv * 32)      * 32];
    unsigned short* lA1 = &Asm[(wv * 32 + 16) * 32];
    unsigned short* lB0 = &Bsm[(wv * 32)      * 32];
    unsigned short* lB1 = &Bsm[(wv * 32 + 16) * 32];

    f32x4 acc[4][4];
#pragma unroll
    for (int i = 0; i < 4; ++i)
#pragma unroll
        for (int j = 0; j < 4; ++j)
            acc[i][j] = (f32x4){0.f, 0.f, 0.f, 0.f};

    for (int k0 = 0; k0 < K; k0 += 32) {
        __syncthreads();
        gl_lds16(gA0 + k0, lA0);
        gl_lds16(gA1 + k0, lA1);
        gl_lds16(gB0 + k0, lB0);
        gl_lds16(gB1 + k0, lB1);
        __syncthreads();

        short8 af[4], bfr[4];
#pragma unroll
        for (int mt = 0; mt < 4; ++mt) {
            int m = wm * 64 + mt * 16 + ln;
            af[mt] = *(const short8*)&Asm[m * 32 + q * 8];
        }
#pragma unroll
        for (int nt = 0; nt < 4; ++nt) {
            int n = wn * 64 + nt * 16 + ln;
            bfr[nt] = *(const short8*)&Bsm[n * 32 + q * 8];
        }
#pragma unroll
        for (int mt = 0; mt < 4; ++mt)
#pragma unroll
            for (int nt = 0; nt < 4; ++nt)
                acc[mt][nt] = __builtin_amdgcn_mfma_f32_16x16x32_bf16(
                    af[mt], bfr[nt], acc[mt][nt], 0, 0, 0);
    }

    const int is32 = is32s;
#pragma unroll
    for (int mt = 0; mt < 4; ++mt) {
#pragma unroll
        for (int nt = 0; nt < 4; ++nt) {
            const int col = blockIdx.x * 128 + wn * 64 + nt * 16 + ln;
            const int rowb = blockIdx.y * 128 + wm * 64 + mt * 16 + q * 4;
#pragma unroll
            for (int r = 0; r < 4; ++r) {
                const long o = (long)(rowb + r) * N + col;
                if (is32) ((float*)out)[o] = acc[mt][nt][r];
                else      ((bf16*)out)[o] = __float2bfloat16(acc[mt][nt][r]);
            }
        }
    }
}

// ---------------------------------------------------------------------------
extern "C" void kernel_launch(void* const* d_in, const int* in_sizes, int n_in,
                              void* d_out, int out_size, void* d_ws, size_t ws_size,
                              hipStream_t stream)
{
    const size_t HD   = (size_t)BHc * Nc * DKc;   // 786432
    const size_t HDh  = HD / 2;                   // float-slots for HD bf16
    const size_t MAT  = (size_t)Nc * Nc;          // 589824
    const size_t MATS = (size_t)BHc * MAT;        // 9437184
    const long   HSTR = (long)Nc * DKc;           // 49152 per-head stride

    float* ws = (float*)d_ws;
    size_t off = 0;
    auto alloc = [&](size_t n) { float* p = ws + off; off += n; return p; };

    bf16* xb  = (bf16*)alloc(HDh);
    bf16* w1b = (bf16*)alloc(HDh);   // w1b/w2b adjacent -> merged transpose
    bf16* w2b = (bf16*)alloc(HDh);
    bf16* w1t = (bf16*)alloc(HDh);
    bf16* w2t = (bf16*)alloc(HDh);
    bf16* pwb = (bf16*)alloc((size_t)Dc * Dc / 2);
    bf16* pwt = (bf16*)alloc((size_t)Dc * Dc / 2);
    float* smallf = alloc(192);
    // q1|q2 and k1|k2 adjacent -> single merged S-GEMM launch (32 heads)
    bf16* q1b = (bf16*)alloc(HDh); bf16* q2b = (bf16*)alloc(HDh);
    bf16* k1b = (bf16*)alloc(HDh); bf16* k2b = (bf16*)alloc(HDh);
    bf16* v1b = (bf16*)alloc(HDh); bf16* v2b = (bf16*)alloc(HDh);  // adjacent
    bf16* v1t = (bf16*)alloc(HDh); bf16* v2t = (bf16*)alloc(HDh);  // adjacent
    bf16* trt = (bf16*)alloc(HDh);
    float* S1   = alloc(MATS);       // S1/S2 adjacent -> merged softmax + S-GEMM
    float* S2   = alloc(MATS);
    float* Smix = alloc(MATS);       // region reused: A1tb|A2tb, then Smix
    bf16* A1b = (bf16*)alloc(MATS / 2);  // A1b/A2b adjacent
    bf16* A2b = (bf16*)alloc(MATS / 2);
    bf16* Crb = (bf16*)alloc(MATS / 2);  // Crb/Clb adjacent (merged launch)
    bf16* Clb = (bf16*)alloc(MATS / 2);
    bf16* yb1 = (bf16*)alloc(HDh);
    bf16* yc  = (bf16*)alloc(HDh);

    // aliases into dead regions
    bf16* A1tb = (bf16*)Smix;            // live steps 3-4 (dead once gates writes Smix)
    bf16* A2tb = ((bf16*)Smix) + MATS;
    bf16* Ab   = (bf16*)S1;              // S1 dead after gates

    const size_t NEED_BYTES = off * sizeof(float);
    if (ws_size < NEED_BYTES) {
        fill_sentinel<<<dim3(3072), 256, 0, stream>>>((unsigned short*)d_out);
        return;
    }

    // 0. normalize inputs
    convert_all<<<dim3(3072), 256, 0, stream>>>(
        d_in[0], d_in[1], d_in[2], d_in[3], d_in[4], d_in[5], d_in[6], d_in[7],
        d_in[8], xb, w1b, w2b, pwb, smallf);

    // 1. merged W transposes; pw transpose; merged QKV; merged v transposes
    transpose_bf16<<<dim3(24, 8, 2), 256, 0, stream>>>(
        (const unsigned short*)w1b, (unsigned short*)w1t, Dc, 3 * Dc, (long)HD, (long)HD);
    transpose_bf16<<<dim3(8, 8, 1), 256, 0, stream>>>(
        (const unsigned short*)pwb, (unsigned short*)pwt, Dc, Dc, 0, 0);
    qkv_mfma<<<dim3(12, 12, 2), 256, 0, stream>>>(
        xb, w1t, w2t, q1b, k1b, v1b, q2b, k2b, v2b);
    transpose_bf16<<<dim3(1, 12, 2 * BHc), 256, 0, stream>>>(
        (const unsigned short*)v1b, (unsigned short*)v1t, Nc, DKc, HSTR, HSTR);

    // 2. S = scale * q @ k^T — single 32-batch launch
    gemm_nt_mfma<0, float><<<dim3(6, 6, 2 * BHc), 256, 0, stream>>>(
        q1b, k1b, S1, Nc, Nc, DKc, HSTR, HSTR, (long)MAT, SCALE);

    // 3. merged softmax S1|S2 -> A1b|A2b; merged transposes -> A1tb|A2tb
    softmax_rows<bf16><<<2 * BHc * Nc, 256, 0, stream>>>(S1, A1b);
    transpose_bf16<<<dim3(12, 12, 2 * BHc), 256, 0, stream>>>(
        (const unsigned short*)A1b, (unsigned short*)A1tb, Nc, Nc, (long)MAT, (long)MAT);

    // 4. Cr|Cl in ONE 32-batch launch (Bt batch = z^16; C regions adjacent)
    gemm_nt_mfma<1, bf16, 1><<<dim3(6, 6, 2 * BHc), 256, 0, stream>>>(
        A1b, A1tb, Crb, Nc, Nc, Nc, (long)MAT, (long)MAT, (long)MAT, 1.f);

    // 5. gates + Smix (2 elem/thread, validated 138 µs)
    gates_smix<<<dim3(24, 48, BHc), 256, 0, stream>>>(S1, S2, Crb, Clb, Smix, smallf);

    // 6. A = softmax(Smix) -> bf16 (into S1 alias)
    softmax_rows<bf16><<<BHc * Nc, 256, 0, stream>>>(Smix, Ab);

    // 7. merged: transport = A2 @ v2 -> trt (transposed epilogue, z<16)
    //            y_base   = A  @ v1 -> yb1 (z>=16)
    gemm_n64_pair<<<dim3(1, 6, 2 * BHc), 256, 0, stream>>>(
        A2b, v2t, trt, Ab, v1t, yb1, Nc, Nc, (long)MAT, HSTR, HSTR);

    // 8. y_chain GEMM with fused combine + permute -> yc
    gemm_n64_combine<<<dim3(1, 6, BHc), 256, 0, stream>>>(
        A1b, trt, yb1, smallf, yc, Nc, Nc, (long)MAT, HSTR);

    // 9. proj via MFMA + dtype-aware store
    proj_mfma<<<dim3(4, 12, 1), 256, 0, stream>>>(yc, pwt, d_in[0], d_out);
}